// Round 1
// baseline (17.437 us; speedup 1.0000x reference)
//
#include <hip/hip_runtime.h>

// Problem: B=128, L=98, H=64, W=64. Only channels 96/97 matter.
// out[0]            = eye_loss (scalar)
// out[1   .. 512]   = source_eyes [128,4]  (lm96_x, lm96_y, lm97_x, lm97_y)
// out[513 .. 1024]  = target_eyes [128,4]

#define HW 4096          // 64*64
#define LCH 98
#define INV_CNT (1.0f / 524288.0f)   // 1/(128*64*64)

__device__ __forceinline__ void compute_eye(const float* hm, int idx,
                                            float* ox, float* oy) {
    int px = idx & 63;
    int py = idx >> 6;
    auto gather = [&](int dx, int dy) -> float {
        int x = min(max(px + dx, 0), 63);
        int y = min(max(py + dy, 0), 63);
        return hm[y * 64 + x];
    };
    float dxv = gather(1, 0) - gather(-1, 0);
    float dyv = gather(0, 1) - gather(0, -1);
    bool inside = (px > 0) && (px < 63) && (py > 0) && (py < 63);
    float offx = inside ? (dxv > 0.0f ? 0.25f : (dxv < 0.0f ? -0.25f : 0.0f)) : 0.0f;
    float offy = inside ? (dyv > 0.0f ? 0.25f : (dyv < 0.0f ? -0.25f : 0.0f)) : 0.0f;
    *ox = ((float)px + 0.5f + offx) * 4.0f;   // (px + 1 + off - 0.5) * 4
    *oy = ((float)py + 0.5f + offy) * 4.0f;
}

__global__ __launch_bounds__(256)
void eye_loss_kernel(const float* __restrict__ src,
                     const float* __restrict__ tgt,
                     float* __restrict__ out) {
    const int tid = threadIdx.x;
    const int bid = blockIdx.x;          // 0..255
    const int b = bid >> 1;              // batch
    const int l = bid & 1;               // 0 -> ch96, 1 -> ch97
    const size_t base = ((size_t)b * LCH + 96 + l) * HW;

    const float* sch = src + base;
    const float* tch = tgt + base;

    // per-thread scan: 4 float4 loads each = 16 elements, increasing index order
    float sBestV = -INFINITY, tBestV = -INFINITY;
    int   sBestI = 0, tBestI = 0;
    float lsum = 0.0f;

    #pragma unroll
    for (int k = 0; k < 4; ++k) {
        int e = (k * 256 + tid) * 4;     // element index, coalesced float4
        float4 s = *(const float4*)(sch + e);
        float4 t = *(const float4*)(tch + e);
        float sv[4] = {s.x, s.y, s.z, s.w};
        float tv[4] = {t.x, t.y, t.z, t.w};
        #pragma unroll
        for (int c = 0; c < 4; ++c) {
            float d = sv[c] - tv[c];
            lsum += d * d;
            if (sv[c] > sBestV) { sBestV = sv[c]; sBestI = e + c; }  // strict >: first max wins
            if (tv[c] > tBestV) { tBestV = tv[c]; tBestI = e + c; }
        }
    }

    __shared__ float s_val[256], t_val[256], s_sum[256];
    __shared__ int   s_idx[256], t_idx[256];
    s_val[tid] = sBestV; s_idx[tid] = sBestI;
    t_val[tid] = tBestV; t_idx[tid] = tBestI;
    s_sum[tid] = lsum;
    __syncthreads();

    #pragma unroll
    for (int stride = 128; stride > 0; stride >>= 1) {
        if (tid < stride) {
            float v = s_val[tid + stride]; int i = s_idx[tid + stride];
            if (v > s_val[tid] || (v == s_val[tid] && i < s_idx[tid])) {
                s_val[tid] = v; s_idx[tid] = i;
            }
            v = t_val[tid + stride]; i = t_idx[tid + stride];
            if (v > t_val[tid] || (v == t_val[tid] && i < t_idx[tid])) {
                t_val[tid] = v; t_idx[tid] = i;
            }
            s_sum[tid] += s_sum[tid + stride];
        }
        __syncthreads();
    }

    if (tid == 0) {
        float x, y;
        compute_eye(sch, s_idx[0], &x, &y);
        out[1 + b * 4 + l * 2 + 0] = x;
        out[1 + b * 4 + l * 2 + 1] = y;
        compute_eye(tch, t_idx[0], &x, &y);
        out[513 + b * 4 + l * 2 + 0] = x;
        out[513 + b * 4 + l * 2 + 1] = y;
        atomicAdd(out, s_sum[0] * INV_CNT);
    }
}

extern "C" void kernel_launch(void* const* d_in, const int* in_sizes, int n_in,
                              void* d_out, int out_size, void* d_ws, size_t ws_size,
                              hipStream_t stream) {
    const float* src = (const float*)d_in[0];
    const float* tgt = (const float*)d_in[1];
    float* out = (float*)d_out;

    // zero the loss accumulator (d_out is poisoned once, never re-poisoned;
    // atomic accumulation must start from 0 every call)
    hipMemsetAsync(out, 0, sizeof(float), stream);

    eye_loss_kernel<<<256, 256, 0, stream>>>(src, tgt, out);
}